// Round 2
// baseline (356.455 us; speedup 1.0000x reference)
//
#include <hip/hip_runtime.h>
#include <hip/hip_bf16.h>

// DistMult relational decoder:
//   out[e] = sigmoid( sum_d z[src[e],d] * rel[rel_id[e],d] * z[dst[e],d] )
// N_NODES=100000, E=2000000, D=128, REL_TYPES=64, all fp32.
//
// Strategy: 32 lanes cooperate per edge. Each lane loads one float4 (16 B)
// of the src row, dst row, and rel row -> 512 B coalesced row reads.
// Cross-lane reduce via __shfl_down (width 32), lane 0 writes sigmoid.
// z table = 51.2 MB -> Infinity-Cache resident; rel = 32 KB -> L1/L2.

#define LANES_PER_EDGE 32

__global__ __launch_bounds__(256) void distmult_kernel(
    const float* __restrict__ z,
    const int* __restrict__ src_idx,
    const int* __restrict__ dst_idx,
    const int* __restrict__ rel_id,
    const float* __restrict__ rel,
    float* __restrict__ out,
    int E)
{
    const int gtid = blockIdx.x * blockDim.x + threadIdx.x;
    const int e    = gtid >> 5;          // edge handled by this 32-lane group
    const int lane = threadIdx.x & 31;   // 0..31 within the group
    if (e >= E) return;

    const int s = src_idx[e];
    const int d = dst_idx[e];
    const int r = rel_id[e];

    const float4* __restrict__ zs = (const float4*)(z   + (size_t)s * 128);
    const float4* __restrict__ zd = (const float4*)(z   + (size_t)d * 128);
    const float4* __restrict__ rr = (const float4*)(rel + (size_t)r * 128);

    const float4 a = zs[lane];
    const float4 b = zd[lane];
    const float4 c = rr[lane];

    float v = a.x * c.x * b.x
            + a.y * c.y * b.y
            + a.z * c.z * b.z
            + a.w * c.w * b.w;

    // reduce across the 32 lanes of this edge-group
    #pragma unroll
    for (int off = 16; off > 0; off >>= 1)
        v += __shfl_down(v, off, 32);

    if (lane == 0)
        out[e] = 1.0f / (1.0f + __expf(-v));
}

extern "C" void kernel_launch(void* const* d_in, const int* in_sizes, int n_in,
                              void* d_out, int out_size, void* d_ws, size_t ws_size,
                              hipStream_t stream) {
    const float* z       = (const float*)d_in[0];
    const int*   eidx    = (const int*)d_in[1];   // [2, E] flat: src then dst
    const int*   rel_id  = (const int*)d_in[2];
    const float* rel     = (const float*)d_in[3];
    float*       out     = (float*)d_out;

    const int E = in_sizes[2];            // 2,000,000
    const int* src_idx = eidx;
    const int* dst_idx = eidx + E;

    const int threads = 256;
    const int edges_per_block = threads / LANES_PER_EDGE;   // 8
    const int blocks = (E + edges_per_block - 1) / edges_per_block;

    distmult_kernel<<<blocks, threads, 0, stream>>>(
        z, src_idx, dst_idx, rel_id, rel, out, E);
}

// Round 3
// 341.060 us; speedup vs baseline: 1.0451x; 1.0451x over previous
//
#include <hip/hip_runtime.h>
#include <hip/hip_bf16.h>

// DistMult relational decoder:
//   out[e] = sigmoid( sum_d z[src[e],d] * rel[rel_id[e],d] * z[dst[e],d] )
// N_NODES=100000, E=2000000, D=128, REL_TYPES=64, all fp32.
//
// R3: 16 lanes per edge (4 edges per wave64). Each lane loads TWO float4s
// from each of src-row / dst-row / rel-row -> 6 independent 16 B loads in
// flight per lane (6 KB per wave) before any arithmetic, to hide L2/L3
// gather latency (R2 showed VALUBusy=44%, FETCH=971 MB, 3.69 TB/s -> half
// the time stalled on vmcnt with only 3 KB/wave outstanding).
// Reduction: 4-step __shfl_down over width 16.

__global__ __launch_bounds__(256) void distmult_kernel(
    const float* __restrict__ z,
    const int* __restrict__ src_idx,
    const int* __restrict__ dst_idx,
    const int* __restrict__ rel_id,
    const float* __restrict__ rel,
    float* __restrict__ out,
    int E)
{
    const int gtid = blockIdx.x * blockDim.x + threadIdx.x;
    const int e    = gtid >> 4;          // edge handled by this 16-lane group
    const int lane = threadIdx.x & 15;   // 0..15 within the group
    if (e >= E) return;

    const int s = src_idx[e];
    const int d = dst_idx[e];
    const int r = rel_id[e];

    const float4* __restrict__ zs = (const float4*)(z   + (size_t)s * 128);
    const float4* __restrict__ zd = (const float4*)(z   + (size_t)d * 128);
    const float4* __restrict__ rr = (const float4*)(rel + (size_t)r * 128);

    // 6 independent gathers — compiler hoists all before first use.
    const float4 a0 = zs[lane];
    const float4 a1 = zs[lane + 16];
    const float4 b0 = zd[lane];
    const float4 b1 = zd[lane + 16];
    const float4 c0 = rr[lane];
    const float4 c1 = rr[lane + 16];

    float v = a0.x * c0.x * b0.x
            + a0.y * c0.y * b0.y
            + a0.z * c0.z * b0.z
            + a0.w * c0.w * b0.w
            + a1.x * c1.x * b1.x
            + a1.y * c1.y * b1.y
            + a1.z * c1.z * b1.z
            + a1.w * c1.w * b1.w;

    // reduce across the 16 lanes of this edge-group
    #pragma unroll
    for (int off = 8; off > 0; off >>= 1)
        v += __shfl_down(v, off, 16);

    if (lane == 0)
        out[e] = 1.0f / (1.0f + __expf(-v));
}

extern "C" void kernel_launch(void* const* d_in, const int* in_sizes, int n_in,
                              void* d_out, int out_size, void* d_ws, size_t ws_size,
                              hipStream_t stream) {
    const float* z       = (const float*)d_in[0];
    const int*   eidx    = (const int*)d_in[1];   // [2, E] flat: src then dst
    const int*   rel_id  = (const int*)d_in[2];
    const float* rel     = (const float*)d_in[3];
    float*       out     = (float*)d_out;

    const int E = in_sizes[2];            // 2,000,000
    const int* src_idx = eidx;
    const int* dst_idx = eidx + E;

    const int threads = 256;
    const int edges_per_block = threads / 16;   // 16 edges per block
    const int blocks = (E + edges_per_block - 1) / edges_per_block;

    distmult_kernel<<<blocks, threads, 0, stream>>>(
        z, src_idx, dst_idx, rel_id, rel, out, E);
}

// Round 4
// 229.354 us; speedup vs baseline: 1.5542x; 1.4870x over previous
//
#include <hip/hip_runtime.h>
#include <hip/hip_bf16.h>
#include <hip/hip_fp16.h>

// DistMult relational decoder:
//   out[e] = sigmoid( sum_d z[src[e],d] * rel[rel_id[e],d] * z[dst[e],d] )
// N_NODES=100000, E=2000000, D=128, REL_TYPES=64, all fp32.
//
// R4: the gather path is bandwidth-bound on L2-miss traffic (R3: FETCH=945MB
// @ 3.8 TB/s, more ILP bought only 5%). Halve gathered bytes: per-launch
// pass converts z (51.2 MB fp32) -> fp16 (25.6 MB) in d_ws; gather kernel
// reads 256 B rows (4 cache lines) instead of 512 B (8 lines). rel stays
// fp32 (32 KB, cache-resident). fp16 keeps absmax ~3e-3 << 2e-2 threshold
// (bf16 would be marginal). Falls back to fp32 gather if ws too small.

// ---- pass 1: z fp32 -> fp16 into workspace (8 elems / thread) ----
__global__ __launch_bounds__(256) void convert_kernel(
    const float* __restrict__ z, __half* __restrict__ zh, int n8)
{
    const int i = blockIdx.x * blockDim.x + threadIdx.x;
    if (i >= n8) return;
    const float4 f0 = ((const float4*)z)[2 * i];
    const float4 f1 = ((const float4*)z)[2 * i + 1];
    union { __half2 h2[4]; uint4 u; } o;
    o.h2[0] = __floats2half2_rn(f0.x, f0.y);
    o.h2[1] = __floats2half2_rn(f0.z, f0.w);
    o.h2[2] = __floats2half2_rn(f1.x, f1.y);
    o.h2[3] = __floats2half2_rn(f1.z, f1.w);
    ((uint4*)zh)[i] = o.u;
}

// ---- pass 2: gather + dot + sigmoid, fp16 z rows ----
// 16 lanes per edge; each lane covers elements [lane*8, lane*8+8):
//   1x uint4 (8 halves) from src row, 1x from dst row, 2x float4 from rel.
__global__ __launch_bounds__(256) void distmult_f16_kernel(
    const __half* __restrict__ zh,
    const int* __restrict__ src_idx,
    const int* __restrict__ dst_idx,
    const int* __restrict__ rel_id,
    const float* __restrict__ rel,
    float* __restrict__ out,
    int E)
{
    const int gtid = blockIdx.x * blockDim.x + threadIdx.x;
    const int e    = gtid >> 4;
    const int lane = threadIdx.x & 15;
    if (e >= E) return;

    const int s = src_idx[e];
    const int d = dst_idx[e];
    const int r = rel_id[e];

    union { uint4 u; __half2 h2[4]; } A, B;
    A.u = ((const uint4*)(zh + (size_t)s * 128))[lane];
    B.u = ((const uint4*)(zh + (size_t)d * 128))[lane];
    const float4* rr = (const float4*)(rel + (size_t)r * 128);
    const float4 r0 = rr[2 * lane];
    const float4 r1 = rr[2 * lane + 1];

    const float2 a0 = __half22float2(A.h2[0]);
    const float2 a1 = __half22float2(A.h2[1]);
    const float2 a2 = __half22float2(A.h2[2]);
    const float2 a3 = __half22float2(A.h2[3]);
    const float2 b0 = __half22float2(B.h2[0]);
    const float2 b1 = __half22float2(B.h2[1]);
    const float2 b2 = __half22float2(B.h2[2]);
    const float2 b3 = __half22float2(B.h2[3]);

    float v = a0.x * r0.x * b0.x
            + a0.y * r0.y * b0.y
            + a1.x * r0.z * b1.x
            + a1.y * r0.w * b1.y
            + a2.x * r1.x * b2.x
            + a2.y * r1.y * b2.y
            + a3.x * r1.z * b3.x
            + a3.y * r1.w * b3.y;

    #pragma unroll
    for (int off = 8; off > 0; off >>= 1)
        v += __shfl_down(v, off, 16);

    if (lane == 0)
        out[e] = 1.0f / (1.0f + __expf(-v));
}

// ---- fallback: fp32 gather (R3 kernel) if workspace too small ----
__global__ __launch_bounds__(256) void distmult_f32_kernel(
    const float* __restrict__ z,
    const int* __restrict__ src_idx,
    const int* __restrict__ dst_idx,
    const int* __restrict__ rel_id,
    const float* __restrict__ rel,
    float* __restrict__ out,
    int E)
{
    const int gtid = blockIdx.x * blockDim.x + threadIdx.x;
    const int e    = gtid >> 4;
    const int lane = threadIdx.x & 15;
    if (e >= E) return;

    const int s = src_idx[e];
    const int d = dst_idx[e];
    const int r = rel_id[e];

    const float4* zs = (const float4*)(z   + (size_t)s * 128);
    const float4* zd = (const float4*)(z   + (size_t)d * 128);
    const float4* rr = (const float4*)(rel + (size_t)r * 128);

    const float4 a0 = zs[lane];
    const float4 a1 = zs[lane + 16];
    const float4 b0 = zd[lane];
    const float4 b1 = zd[lane + 16];
    const float4 c0 = rr[lane];
    const float4 c1 = rr[lane + 16];

    float v = a0.x * c0.x * b0.x + a0.y * c0.y * b0.y
            + a0.z * c0.z * b0.z + a0.w * c0.w * b0.w
            + a1.x * c1.x * b1.x + a1.y * c1.y * b1.y
            + a1.z * c1.z * b1.z + a1.w * c1.w * b1.w;

    #pragma unroll
    for (int off = 8; off > 0; off >>= 1)
        v += __shfl_down(v, off, 16);

    if (lane == 0)
        out[e] = 1.0f / (1.0f + __expf(-v));
}

extern "C" void kernel_launch(void* const* d_in, const int* in_sizes, int n_in,
                              void* d_out, int out_size, void* d_ws, size_t ws_size,
                              hipStream_t stream) {
    const float* z       = (const float*)d_in[0];
    const int*   eidx    = (const int*)d_in[1];   // [2, E] flat: src then dst
    const int*   rel_id  = (const int*)d_in[2];
    const float* rel     = (const float*)d_in[3];
    float*       out     = (float*)d_out;

    const int nz = in_sizes[0];           // 12,800,000 (= N_NODES * 128)
    const int E  = in_sizes[2];           // 2,000,000
    const int* src_idx = eidx;
    const int* dst_idx = eidx + E;

    const int threads = 256;
    const int edges_per_block = threads / 16;
    const int blocks = (E + edges_per_block - 1) / edges_per_block;

    const size_t need = (size_t)nz * sizeof(__half);
    if (ws_size >= need) {
        __half* zh = (__half*)d_ws;
        const int n8 = nz / 8;
        convert_kernel<<<(n8 + threads - 1) / threads, threads, 0, stream>>>(z, zh, n8);
        distmult_f16_kernel<<<blocks, threads, 0, stream>>>(
            zh, src_idx, dst_idx, rel_id, rel, out, E);
    } else {
        distmult_f32_kernel<<<blocks, threads, 0, stream>>>(
            z, src_idx, dst_idx, rel_id, rel, out, E);
    }
}